// Round 11
// baseline (135.077 us; speedup 1.0000x reference)
//
#include <hip/hip_runtime.h>

typedef __bf16 bf16x8 __attribute__((ext_vector_type(8)));
typedef __bf16 bf16x4 __attribute__((ext_vector_type(4)));
typedef __bf16 bf16x2 __attribute__((ext_vector_type(2)));
typedef float f32x4 __attribute__((ext_vector_type(4)));
typedef short s16x4 __attribute__((ext_vector_type(4)));

#define NB 4
#define NC 64
#define NN 4096
#define SPLIT 8   // key-dim splits for flash

// sc folded into Q at qkv time: softmax uses exp2(q.k * 0.125 * log2(e))
#define QSCALE (0.125f * 1.44269504088896340736f)

#if __has_builtin(__builtin_amdgcn_exp2f)
#define EXP2(x) __builtin_amdgcn_exp2f(x)   // raw v_exp_f32; inputs are O(1)
#else
#define EXP2(x) exp2f(x)
#endif

// ---------------------------------------------------------------------------
// Kernel 1: QKV projection (R7-exact, known good).
// x:[B,C,N] fp32 -> Q (pre-scaled), K bf16 [B,N,C]; V bf16 [B,C,N]
// grid(8, B, 24): z -> {q,k,v} x 8-output group.  768 blocks.
// ---------------------------------------------------------------------------
__global__ __launch_bounds__(256) void qkv_kernel(
    const float* __restrict__ x, const float* __restrict__ wqkv,
    const float* __restrict__ bqkv,
    __bf16* __restrict__ Qg, __bf16* __restrict__ Kg, __bf16* __restrict__ Vg)
{
  const int tid = threadIdx.x;
  const int b = blockIdx.y;
  const int z = blockIdx.z;
  const int tsel = z >> 3;           // 0=q, 1=k, 2=v
  const int obase = (z & 7) * 8;     // which 8 output channels
  const int n = blockIdx.x * 512 + tid * 2;   // this thread: n, n+1
  const float wscale = (tsel == 0) ? QSCALE : 1.0f;

  __shared__ float wsh[8 * 64];      // 512 floats: 2 per thread
  __shared__ float bsh[8];
  wsh[tid]       = wqkv[(tsel * 64 + obase) * 64 + tid] * wscale;
  wsh[tid + 256] = wqkv[(tsel * 64 + obase) * 64 + tid + 256] * wscale;
  if (tid < 8) bsh[tid] = bqkv[tsel * 64 + obase + tid] * wscale;
  __syncthreads();

  float xa[64], xb[64];
#pragma unroll
  for (int c = 0; c < 64; c++) {
    const float2 t = *(const float2*)&x[((size_t)(b * 64 + c)) * NN + n];
    xa[c] = t.x; xb[c] = t.y;        // 8B/lane coalesced
  }

  float aa[8], ab[8];
#pragma unroll
  for (int j = 0; j < 8; j++) { aa[j] = bsh[j]; ab[j] = bsh[j]; }
#pragma unroll
  for (int c4 = 0; c4 < 64; c4 += 4) {
#pragma unroll
    for (int j = 0; j < 8; j++) {
      const float4 wv = *(const float4*)&wsh[j * 64 + c4];  // broadcast read
      aa[j] = fmaf(wv.x, xa[c4 + 0], aa[j]);
      aa[j] = fmaf(wv.y, xa[c4 + 1], aa[j]);
      aa[j] = fmaf(wv.z, xa[c4 + 2], aa[j]);
      aa[j] = fmaf(wv.w, xa[c4 + 3], aa[j]);
      ab[j] = fmaf(wv.x, xb[c4 + 0], ab[j]);
      ab[j] = fmaf(wv.y, xb[c4 + 1], ab[j]);
      ab[j] = fmaf(wv.z, xb[c4 + 2], ab[j]);
      ab[j] = fmaf(wv.w, xb[c4 + 3], ab[j]);
    }
  }

  if (tsel == 2) {
#pragma unroll
    for (int j = 0; j < 8; j++) {
      bf16x2 pv;
      pv[0] = (__bf16)aa[j]; pv[1] = (__bf16)ab[j];
      *(bf16x2*)(Vg + ((size_t)(b * 64 + obase + j)) * NN + n) = pv;
    }
  } else {
    __bf16* base = (tsel == 0 ? Qg : Kg);
    bf16x8 p0, p1;
#pragma unroll
    for (int j = 0; j < 8; j++) { p0[j] = (__bf16)aa[j]; p1[j] = (__bf16)ab[j]; }
    *(bf16x8*)(base + ((size_t)(b * NN + n)) * 64 + obase) = p0;
    *(bf16x8*)(base + ((size_t)(b * NN + n + 1)) * 64 + obase) = p1;
  }
}

// ---------------------------------------------------------------------------
// Kernel 2: flash attention, split-K, max-free softmax.
// R10 math (verified): S^T = mfma_16x16x32(kf,qf) -> exp2 -> P packed in
// VGPRs (S^T C/D layout == B-operand layout of mfma_16x16x16bf16) -> PV as
// 4 chained K=16 MFMAs with A = V^T b64 LDS frags.
// NEW vs R10: K-fragments read DIRECT FROM GLOBAL (well-shaped b128 pairs,
// L1/L2-hot across 4 waves x 32 q-blocks per (b,s)); only V staged in LDS,
// two 64-key sub-tiles per barrier pair (BK=128) -> half the barriers,
// half the staging vmcnt drain, LDS pipe/tile ~108cyc vs 240.
// Opart:[S,B,C,N] bf16 (unnorm), lpart:[S,B,N] float.
// grid(32, B, SPLIT), 256 thr = 4 waves; wave owns 32 q, block 128 q.
// ---------------------------------------------------------------------------
__global__ __launch_bounds__(256) void flash_kernel(
    const __bf16* __restrict__ Q, const __bf16* __restrict__ K,
    const __bf16* __restrict__ V, __bf16* __restrict__ Opart,
    float* __restrict__ lpart)
{
  const int b = blockIdx.y;
  const int s = blockIdx.z;
  const int tid = threadIdx.x;
  const int wave = tid >> 6;
  const int lane = tid & 63;
  const int quad = lane >> 4;
  const int l16 = lane & 15;

  __shared__ __bf16 Vt[2][64 * 72];   // [sub][c][key], padded rows

  const int q0 = blockIdx.x * 128 + wave * 32;

  // Q fragments (registers, loaded once)
  bf16x8 qf[2][2];
#pragma unroll
  for (int qt = 0; qt < 2; qt++) {
    const __bf16* qrow = Q + ((size_t)(b * NN + q0 + qt * 16 + l16)) * 64;
    qf[qt][0] = *(const bf16x8*)(qrow + quad * 8);
    qf[qt][1] = *(const bf16x8*)(qrow + 32 + quad * 8);
  }

  f32x4 acc[2][4];    // O^T acc: row c = ct*16+quad*4+r, col q = qt*16+l16
#pragma unroll
  for (int qt = 0; qt < 2; qt++)
#pragma unroll
    for (int ct = 0; ct < 4; ct++) acc[qt][ct] = (f32x4){0.f, 0.f, 0.f, 0.f};
  float l[2] = {0.f, 0.f};

  const int kbeg = s * (NN / SPLIT);
  const int kend = kbeg + (NN / SPLIT);
#pragma unroll 1
  for (int kt0 = kbeg; kt0 < kend; kt0 += 128) {
    __syncthreads();
    // stage V for both 64-key sub-tiles (1 b128 write/thread/sub-tile x2)
#pragma unroll
    for (int sub = 0; sub < 2; sub++) {
#pragma unroll
      for (int it = 0; it < 2; it++) {
        const int chunk = tid + it * 256;        // 512 chunks of 8 bf16
        const int row = chunk >> 3, col8 = (chunk & 7) * 8;
        *(bf16x8*)(&Vt[sub][row * 72 + col8]) =
            *(const bf16x8*)(V + ((size_t)(b * 64 + row)) * NN +
                             kt0 + sub * 64 + col8);
      }
    }
    __syncthreads();

#pragma unroll
    for (int sub = 0; sub < 2; sub++) {
      const int kt = kt0 + sub * 64;
      const __bf16* Vb = Vt[sub];

      // ---- S^T = K Q^T, P packed into registers; K direct from global ----
      s16x4 pk[4][2];
#pragma unroll
      for (int t = 0; t < 4; t++) {
        const __bf16* krow =
            K + ((size_t)(b * NN + kt + t * 16 + l16)) * 64 + quad * 8;
        const bf16x8 kf0 = *(const bf16x8*)(krow);
        const bf16x8 kf1 = *(const bf16x8*)(krow + 32);
#pragma unroll
        for (int qt = 0; qt < 2; qt++) {
          f32x4 z = (f32x4){0.f, 0.f, 0.f, 0.f};
          z = __builtin_amdgcn_mfma_f32_16x16x32_bf16(kf0, qf[qt][0], z, 0, 0, 0);
          z = __builtin_amdgcn_mfma_f32_16x16x32_bf16(kf1, qf[qt][1], z, 0, 0, 0);
          const float p0 = EXP2(z[0]), p1 = EXP2(z[1]);
          const float p2 = EXP2(z[2]), p3 = EXP2(z[3]);
          l[qt] += (p0 + p1) + (p2 + p3);
          bf16x4 pv;
          pv[0] = (__bf16)p0; pv[1] = (__bf16)p1;
          pv[2] = (__bf16)p2; pv[3] = (__bf16)p3;
          pk[t][qt] = __builtin_bit_cast(s16x4, pv);
        }
      }

      // ---- O^T += V^T P^T : K=16 MFMAs, P straight from registers --------
#pragma unroll
      for (int kg = 0; kg < 4; kg++) {
#pragma unroll
        for (int ct = 0; ct < 4; ct++) {
          const bf16x4 va =
              *(const bf16x4*)(&Vb[(ct * 16 + l16) * 72 + kg * 16 + quad * 4]);
          const s16x4 a = __builtin_bit_cast(s16x4, va);
          acc[0][ct] = __builtin_amdgcn_mfma_f32_16x16x16bf16_1k(
              a, pk[kg][0], acc[0][ct], 0, 0, 0);
          acc[1][ct] = __builtin_amdgcn_mfma_f32_16x16x16bf16_1k(
              a, pk[kg][1], acc[1][ct], 0, 0, 0);
        }
      }
    }
  }

  // epilogue: 2 shuffles per q-tile for l; O^T stores (16 lanes along n)
#pragma unroll
  for (int qt = 0; qt < 2; qt++) {
    float lr = l[qt];
    lr += __shfl_xor(lr, 16);
    lr += __shfl_xor(lr, 32);
    if (quad == 0)
      lpart[((size_t)(s * NB + b)) * NN + q0 + qt * 16 + l16] = lr;
#pragma unroll
    for (int ct = 0; ct < 4; ct++)
#pragma unroll
      for (int r = 0; r < 4; r++)
        Opart[(((size_t)(s * NB + b)) * 64 + ct * 16 + quad * 4 + r) * NN +
              q0 + qt * 16 + l16] = (__bf16)acc[qt][ct][r];
  }
}

// ---------------------------------------------------------------------------
// Kernel 3: fused combine + output projection + bias + residual (R7-exact).
// Opart:[S,B,C,N] bf16 -> transpose-free combine stage.
// grid(128, B) = 512 blocks; block = 32-n tile x all 64 channels.
// ---------------------------------------------------------------------------
__global__ __launch_bounds__(256) void combine_proj_kernel(
    const __bf16* __restrict__ Opart, const float* __restrict__ lpart,
    const float* __restrict__ wproj, const float* __restrict__ bproj,
    const float* __restrict__ x, float* __restrict__ out)
{
  const int b = blockIdx.y;
  const int n0 = blockIdx.x * 32;
  const int tid = threadIdx.x;

  __shared__ float Ot[64 * 36];   // [cin][n-tile 32], stride 36
  __shared__ float wT[64 * 66];   // [cin][cout], stride 66
  __shared__ float lsh[32];
  __shared__ float bsh[64];

  if (tid < 32) {
    float lt = 0.f;
#pragma unroll
    for (int s = 0; s < SPLIT; s++)
      lt += lpart[((size_t)(s * NB + b)) * NN + n0 + tid];
    lsh[tid] = 1.0f / lt;
  }
  if (tid < 64) bsh[tid] = bproj[tid];
#pragma unroll
  for (int k = 0; k < 16; k++) {
    const int i = tid + k * 256;        // i = cout*64 + cin
    wT[(i & 63) * 66 + (i >> 6)] = wproj[i];
  }
  __syncthreads();

  // combine stage, transpose-free: thread -> (cin = tid>>2, 8 n's)
  {
    const int c = tid >> 2;
    const int n8 = (tid & 3) * 8;
    float o[8];
#pragma unroll
    for (int j = 0; j < 8; j++) o[j] = 0.f;
#pragma unroll
    for (int s = 0; s < SPLIT; s++) {
      const bf16x8 v = *(const bf16x8*)(
          Opart + (((size_t)(s * NB + b)) * 64 + c) * NN + n0 + n8);
#pragma unroll
      for (int j = 0; j < 8; j++) o[j] += (float)v[j];
    }
#pragma unroll
    for (int j = 0; j < 8; j++) Ot[c * 36 + n8 + j] = o[j] * lsh[n8 + j];
  }
  __syncthreads();

  // micro-GEMM: thread -> 2 couts x 4 n
  const int co = (tid >> 3) * 2;
  const int ng = (tid & 7) * 4;
  float a0[4], a1[4];
#pragma unroll
  for (int j = 0; j < 4; j++) { a0[j] = bsh[co]; a1[j] = bsh[co + 1]; }
  for (int cin = 0; cin < 64; cin++) {
    const float4 ov = *(const float4*)&Ot[cin * 36 + ng];
    const float2 wv = *(const float2*)&wT[cin * 66 + co];
    a0[0] = fmaf(wv.x, ov.x, a0[0]); a0[1] = fmaf(wv.x, ov.y, a0[1]);
    a0[2] = fmaf(wv.x, ov.z, a0[2]); a0[3] = fmaf(wv.x, ov.w, a0[3]);
    a1[0] = fmaf(wv.y, ov.x, a1[0]); a1[1] = fmaf(wv.y, ov.y, a1[1]);
    a1[2] = fmaf(wv.y, ov.z, a1[2]); a1[3] = fmaf(wv.y, ov.w, a1[3]);
  }

  // residual + write (8-lane groups cover 128B contiguous per cout row)
#pragma unroll
  for (int i = 0; i < 2; i++) {
    float* ai = (i == 0) ? a0 : a1;
    const size_t base = ((size_t)(b * 64 + co + i)) * NN + n0 + ng;
    const float4 xr = *(const float4*)&x[base];
    float4 r;
    r.x = ai[0] + xr.x; r.y = ai[1] + xr.y;
    r.z = ai[2] + xr.z; r.w = ai[3] + xr.w;
    *(float4*)&out[base] = r;
  }
}

extern "C" void kernel_launch(void* const* d_in, const int* in_sizes, int n_in,
                              void* d_out, int out_size, void* d_ws, size_t ws_size,
                              hipStream_t stream) {
  const float* x     = (const float*)d_in[0];
  const float* wqkv  = (const float*)d_in[1];
  const float* bqkv  = (const float*)d_in[2];
  const float* wproj = (const float*)d_in[3];
  const float* bproj = (const float*)d_in[4];
  float* out = (float*)d_out;

  // Workspace: Q[0,2M) K[2,4M) V[4,6M) Opart[6,22M) l[23M,23.5M)
  char* ws = (char*)d_ws;
  __bf16* Q     = (__bf16*)(ws);
  __bf16* K     = (__bf16*)(ws + (2u << 20));
  __bf16* V     = (__bf16*)(ws + (4u << 20));
  __bf16* Opart = (__bf16*)(ws + (6u << 20));   // [S,B,C,N] = 16 MiB
  float*  lpart = (float*)(ws + (23u << 20));   // SPLIT*B*N*4 = 512 KiB

  qkv_kernel<<<dim3(8, NB, 24), 256, 0, stream>>>(x, wqkv, bqkv, Q, K, V);
  flash_kernel<<<dim3(32, NB, SPLIT), 256, 0, stream>>>(Q, K, V, Opart, lpart);
  combine_proj_kernel<<<dim3(128, NB), 256, 0, stream>>>(Opart, lpart, wproj,
                                                         bproj, x, out);
}

// Round 12
// 124.685 us; speedup vs baseline: 1.0833x; 1.0833x over previous
//
#include <hip/hip_runtime.h>

typedef __bf16 bf16x8 __attribute__((ext_vector_type(8)));
typedef __bf16 bf16x4 __attribute__((ext_vector_type(4)));
typedef __bf16 bf16x2 __attribute__((ext_vector_type(2)));
typedef float f32x4 __attribute__((ext_vector_type(4)));
typedef short s16x4 __attribute__((ext_vector_type(4)));

#define NB 4
#define NC 64
#define NN 4096
#define SPLIT 16  // key-dim splits for flash (256 keys per block)

// sc folded into Q at qkv time: softmax uses exp2(q.k * 0.125 * log2(e))
#define QSCALE (0.125f * 1.44269504088896340736f)

#if __has_builtin(__builtin_amdgcn_exp2f)
#define EXP2(x) __builtin_amdgcn_exp2f(x)   // raw v_exp_f32; inputs are O(1)
#else
#define EXP2(x) exp2f(x)
#endif

// ---------------------------------------------------------------------------
// Kernel 1: QKV projection (R7-exact, known good).
// x:[B,C,N] fp32 -> Q (pre-scaled), K bf16 [B,N,C]; V bf16 [B,C,N]
// grid(8, B, 24): z -> {q,k,v} x 8-output group.  768 blocks.
// ---------------------------------------------------------------------------
__global__ __launch_bounds__(256) void qkv_kernel(
    const float* __restrict__ x, const float* __restrict__ wqkv,
    const float* __restrict__ bqkv,
    __bf16* __restrict__ Qg, __bf16* __restrict__ Kg, __bf16* __restrict__ Vg)
{
  const int tid = threadIdx.x;
  const int b = blockIdx.y;
  const int z = blockIdx.z;
  const int tsel = z >> 3;           // 0=q, 1=k, 2=v
  const int obase = (z & 7) * 8;     // which 8 output channels
  const int n = blockIdx.x * 512 + tid * 2;   // this thread: n, n+1
  const float wscale = (tsel == 0) ? QSCALE : 1.0f;

  __shared__ float wsh[8 * 64];      // 512 floats: 2 per thread
  __shared__ float bsh[8];
  wsh[tid]       = wqkv[(tsel * 64 + obase) * 64 + tid] * wscale;
  wsh[tid + 256] = wqkv[(tsel * 64 + obase) * 64 + tid + 256] * wscale;
  if (tid < 8) bsh[tid] = bqkv[tsel * 64 + obase + tid] * wscale;
  __syncthreads();

  float xa[64], xb[64];
#pragma unroll
  for (int c = 0; c < 64; c++) {
    const float2 t = *(const float2*)&x[((size_t)(b * 64 + c)) * NN + n];
    xa[c] = t.x; xb[c] = t.y;        // 8B/lane coalesced
  }

  float aa[8], ab[8];
#pragma unroll
  for (int j = 0; j < 8; j++) { aa[j] = bsh[j]; ab[j] = bsh[j]; }
#pragma unroll
  for (int c4 = 0; c4 < 64; c4 += 4) {
#pragma unroll
    for (int j = 0; j < 8; j++) {
      const float4 wv = *(const float4*)&wsh[j * 64 + c4];  // broadcast read
      aa[j] = fmaf(wv.x, xa[c4 + 0], aa[j]);
      aa[j] = fmaf(wv.y, xa[c4 + 1], aa[j]);
      aa[j] = fmaf(wv.z, xa[c4 + 2], aa[j]);
      aa[j] = fmaf(wv.w, xa[c4 + 3], aa[j]);
      ab[j] = fmaf(wv.x, xb[c4 + 0], ab[j]);
      ab[j] = fmaf(wv.y, xb[c4 + 1], ab[j]);
      ab[j] = fmaf(wv.z, xb[c4 + 2], ab[j]);
      ab[j] = fmaf(wv.w, xb[c4 + 3], ab[j]);
    }
  }

  if (tsel == 2) {
#pragma unroll
    for (int j = 0; j < 8; j++) {
      bf16x2 pv;
      pv[0] = (__bf16)aa[j]; pv[1] = (__bf16)ab[j];
      *(bf16x2*)(Vg + ((size_t)(b * 64 + obase + j)) * NN + n) = pv;
    }
  } else {
    __bf16* base = (tsel == 0 ? Qg : Kg);
    bf16x8 p0, p1;
#pragma unroll
    for (int j = 0; j < 8; j++) { p0[j] = (__bf16)aa[j]; p1[j] = (__bf16)ab[j]; }
    *(bf16x8*)(base + ((size_t)(b * NN + n)) * 64 + obase) = p0;
    *(bf16x8*)(base + ((size_t)(b * NN + n + 1)) * 64 + obase) = p1;
  }
}

// ---------------------------------------------------------------------------
// Kernel 2: flash attention, split-K, max-free softmax.
// R10-exact staging shell (Kt+Vt LDS, 2 barriers per 64-key tile — the
// verified local optimum; R8/R9/R11 direct-global variants all regressed)
// + 64 QUERIES/WAVE (qt=4): K-frag and V-frag LDS reads are q-independent,
// so per-query LDS cost halves vs R10.  SPLIT=16 keeps 1024 blocks
// (4/CU, 16 waves/CU).  P stays in registers (S^T C/D layout == B-operand
// of mfma_16x16x16bf16_1k); PV = 4 chained K=16 MFMAs, A = V^T b64 frags.
// Opart:[S,B,C,N] bf16 (unnorm), lpart:[S,B,N] float.
// grid(16, B, SPLIT), 256 thr = 4 waves; wave owns 64 q, block 256 q.
// ---------------------------------------------------------------------------
__global__ __launch_bounds__(256) void flash_kernel(
    const __bf16* __restrict__ Q, const __bf16* __restrict__ K,
    const __bf16* __restrict__ V, __bf16* __restrict__ Opart,
    float* __restrict__ lpart)
{
  const int b = blockIdx.y;
  const int s = blockIdx.z;
  const int tid = threadIdx.x;
  const int wave = tid >> 6;
  const int lane = tid & 63;
  const int quad = lane >> 4;
  const int l16 = lane & 15;

  __shared__ __bf16 Kt[64 * 72];      // [key][c], padded
  __shared__ __bf16 Vt[64 * 72];      // [c][key], padded

  const int q0 = blockIdx.x * 256 + wave * 64;

  // Q fragments for 4 q-tiles (registers, loaded once)
  bf16x8 qf[4][2];
#pragma unroll
  for (int qt = 0; qt < 4; qt++) {
    const __bf16* qrow = Q + ((size_t)(b * NN + q0 + qt * 16 + l16)) * 64;
    qf[qt][0] = *(const bf16x8*)(qrow + quad * 8);
    qf[qt][1] = *(const bf16x8*)(qrow + 32 + quad * 8);
  }

  f32x4 acc[4][4];    // O^T acc: row c = ct*16+quad*4+r, col q = qt*16+l16
#pragma unroll
  for (int qt = 0; qt < 4; qt++)
#pragma unroll
    for (int ct = 0; ct < 4; ct++) acc[qt][ct] = (f32x4){0.f, 0.f, 0.f, 0.f};
  float l[4] = {0.f, 0.f, 0.f, 0.f};

  const int kbeg = s * (NN / SPLIT);
  const int kend = kbeg + (NN / SPLIT);
#pragma unroll 1
  for (int kt0 = kbeg; kt0 < kend; kt0 += 64) {
    __syncthreads();
#pragma unroll
    for (int it = 0; it < 2; it++) {
      const int chunk = tid + it * 256;          // 512 chunks of 8 bf16
      const int row = chunk >> 3, col8 = (chunk & 7) * 8;
      *(bf16x8*)(&Kt[row * 72 + col8]) =
          *(const bf16x8*)(K + ((size_t)(b * NN + kt0 + row)) * 64 + col8);
      *(bf16x8*)(&Vt[row * 72 + col8]) =
          *(const bf16x8*)(V + ((size_t)(b * 64 + row)) * NN + kt0 + col8);
    }
    __syncthreads();

    // ---- S^T = K Q^T, P packed into registers --------------------------
    s16x4 pk[4][4];          // [t][qt]
#pragma unroll
    for (int t = 0; t < 4; t++) {
      const bf16x8 kf0 = *(const bf16x8*)(&Kt[(t * 16 + l16) * 72 + quad * 8]);
      const bf16x8 kf1 = *(const bf16x8*)(&Kt[(t * 16 + l16) * 72 + 32 + quad * 8]);
#pragma unroll
      for (int qt = 0; qt < 4; qt++) {
        f32x4 z = (f32x4){0.f, 0.f, 0.f, 0.f};
        z = __builtin_amdgcn_mfma_f32_16x16x32_bf16(kf0, qf[qt][0], z, 0, 0, 0);
        z = __builtin_amdgcn_mfma_f32_16x16x32_bf16(kf1, qf[qt][1], z, 0, 0, 0);
        const float p0 = EXP2(z[0]), p1 = EXP2(z[1]);
        const float p2 = EXP2(z[2]), p3 = EXP2(z[3]);
        l[qt] += (p0 + p1) + (p2 + p3);
        bf16x4 pv;
        pv[0] = (__bf16)p0; pv[1] = (__bf16)p1;
        pv[2] = (__bf16)p2; pv[3] = (__bf16)p3;
        pk[t][qt] = __builtin_bit_cast(s16x4, pv);
      }
    }

    // ---- O^T += V^T P^T : K=16 MFMAs, P straight from registers --------
#pragma unroll
    for (int kg = 0; kg < 4; kg++) {
#pragma unroll
      for (int ct = 0; ct < 4; ct++) {
        const bf16x4 va =
            *(const bf16x4*)(&Vt[(ct * 16 + l16) * 72 + kg * 16 + quad * 4]);
        const s16x4 a = __builtin_bit_cast(s16x4, va);
#pragma unroll
        for (int qt = 0; qt < 4; qt++)
          acc[qt][ct] = __builtin_amdgcn_mfma_f32_16x16x16bf16_1k(
              a, pk[kg][qt], acc[qt][ct], 0, 0, 0);
      }
    }
  }

  // epilogue: 2 shuffles per q-tile for l; O^T stores (16 lanes along n)
#pragma unroll
  for (int qt = 0; qt < 4; qt++) {
    float lr = l[qt];
    lr += __shfl_xor(lr, 16);
    lr += __shfl_xor(lr, 32);
    if (quad == 0)
      lpart[((size_t)(s * NB + b)) * NN + q0 + qt * 16 + l16] = lr;
#pragma unroll
    for (int ct = 0; ct < 4; ct++)
#pragma unroll
      for (int r = 0; r < 4; r++)
        Opart[(((size_t)(s * NB + b)) * 64 + ct * 16 + quad * 4 + r) * NN +
              q0 + qt * 16 + l16] = (__bf16)acc[qt][ct][r];
  }
}

// ---------------------------------------------------------------------------
// Kernel 3: fused combine + output projection + bias + residual.
// Opart:[S,B,C,N] bf16 -> transpose-free combine stage (SPLIT=16).
// grid(128, B) = 512 blocks; block = 32-n tile x all 64 channels.
// ---------------------------------------------------------------------------
__global__ __launch_bounds__(256) void combine_proj_kernel(
    const __bf16* __restrict__ Opart, const float* __restrict__ lpart,
    const float* __restrict__ wproj, const float* __restrict__ bproj,
    const float* __restrict__ x, float* __restrict__ out)
{
  const int b = blockIdx.y;
  const int n0 = blockIdx.x * 32;
  const int tid = threadIdx.x;

  __shared__ float Ot[64 * 36];   // [cin][n-tile 32], stride 36
  __shared__ float wT[64 * 66];   // [cin][cout], stride 66
  __shared__ float lsh[32];
  __shared__ float bsh[64];

  if (tid < 32) {
    float lt = 0.f;
#pragma unroll
    for (int s = 0; s < SPLIT; s++)
      lt += lpart[((size_t)(s * NB + b)) * NN + n0 + tid];
    lsh[tid] = 1.0f / lt;
  }
  if (tid < 64) bsh[tid] = bproj[tid];
#pragma unroll
  for (int k = 0; k < 16; k++) {
    const int i = tid + k * 256;        // i = cout*64 + cin
    wT[(i & 63) * 66 + (i >> 6)] = wproj[i];
  }
  __syncthreads();

  // combine stage, transpose-free: thread -> (cin = tid>>2, 8 n's)
  {
    const int c = tid >> 2;
    const int n8 = (tid & 3) * 8;
    float o[8];
#pragma unroll
    for (int j = 0; j < 8; j++) o[j] = 0.f;
#pragma unroll
    for (int s = 0; s < SPLIT; s++) {
      const bf16x8 v = *(const bf16x8*)(
          Opart + (((size_t)(s * NB + b)) * 64 + c) * NN + n0 + n8);
#pragma unroll
      for (int j = 0; j < 8; j++) o[j] += (float)v[j];
    }
#pragma unroll
    for (int j = 0; j < 8; j++) Ot[c * 36 + n8 + j] = o[j] * lsh[n8 + j];
  }
  __syncthreads();

  // micro-GEMM: thread -> 2 couts x 4 n
  const int co = (tid >> 3) * 2;
  const int ng = (tid & 7) * 4;
  float a0[4], a1[4];
#pragma unroll
  for (int j = 0; j < 4; j++) { a0[j] = bsh[co]; a1[j] = bsh[co + 1]; }
  for (int cin = 0; cin < 64; cin++) {
    const float4 ov = *(const float4*)&Ot[cin * 36 + ng];
    const float2 wv = *(const float2*)&wT[cin * 66 + co];
    a0[0] = fmaf(wv.x, ov.x, a0[0]); a0[1] = fmaf(wv.x, ov.y, a0[1]);
    a0[2] = fmaf(wv.x, ov.z, a0[2]); a0[3] = fmaf(wv.x, ov.w, a0[3]);
    a1[0] = fmaf(wv.y, ov.x, a1[0]); a1[1] = fmaf(wv.y, ov.y, a1[1]);
    a1[2] = fmaf(wv.y, ov.z, a1[2]); a1[3] = fmaf(wv.y, ov.w, a1[3]);
  }

  // residual + write (8-lane groups cover 128B contiguous per cout row)
#pragma unroll
  for (int i = 0; i < 2; i++) {
    float* ai = (i == 0) ? a0 : a1;
    const size_t base = ((size_t)(b * 64 + co + i)) * NN + n0 + ng;
    const float4 xr = *(const float4*)&x[base];
    float4 r;
    r.x = ai[0] + xr.x; r.y = ai[1] + xr.y;
    r.z = ai[2] + xr.z; r.w = ai[3] + xr.w;
    *(float4*)&out[base] = r;
  }
}

extern "C" void kernel_launch(void* const* d_in, const int* in_sizes, int n_in,
                              void* d_out, int out_size, void* d_ws, size_t ws_size,
                              hipStream_t stream) {
  const float* x     = (const float*)d_in[0];
  const float* wqkv  = (const float*)d_in[1];
  const float* bqkv  = (const float*)d_in[2];
  const float* wproj = (const float*)d_in[3];
  const float* bproj = (const float*)d_in[4];
  float* out = (float*)d_out;

  // Workspace: Q[0,2M) K[2,4M) V[4,6M) Opart[6,38M) lpart[40,41M)
  char* ws = (char*)d_ws;
  __bf16* Q     = (__bf16*)(ws);
  __bf16* K     = (__bf16*)(ws + (2u << 20));
  __bf16* V     = (__bf16*)(ws + (4u << 20));
  __bf16* Opart = (__bf16*)(ws + (6u << 20));   // [S,B,C,N] = 32 MiB
  float*  lpart = (float*)(ws + (40u << 20));   // SPLIT*B*N*4 = 1 MiB

  qkv_kernel<<<dim3(8, NB, 24), 256, 0, stream>>>(x, wqkv, bqkv, Q, K, V);
  flash_kernel<<<dim3(16, NB, SPLIT), 256, 0, stream>>>(Q, K, V, Opart, lpart);
  combine_proj_kernel<<<dim3(128, NB), 256, 0, stream>>>(Opart, lpart, wproj,
                                                         bproj, x, out);
}

// Round 13
// 115.131 us; speedup vs baseline: 1.1733x; 1.0830x over previous
//
#include <hip/hip_runtime.h>

typedef __bf16 bf16x8 __attribute__((ext_vector_type(8)));
typedef __bf16 bf16x4 __attribute__((ext_vector_type(4)));
typedef __bf16 bf16x2 __attribute__((ext_vector_type(2)));
typedef float f32x4 __attribute__((ext_vector_type(4)));
typedef short s16x4 __attribute__((ext_vector_type(4)));

#define NB 4
#define NC 64
#define NN 4096
#define SPLIT 8   // key-dim splits for flash

// sc folded into Q at qkv time: softmax uses exp2(q.k * 0.125 * log2(e))
#define QSCALE (0.125f * 1.44269504088896340736f)

#if __has_builtin(__builtin_amdgcn_exp2f)
#define EXP2(x) __builtin_amdgcn_exp2f(x)   // raw v_exp_f32; inputs are O(1)
#else
#define EXP2(x) exp2f(x)
#endif

// ---------------------------------------------------------------------------
// Kernel 1: QKV projection (R10-exact, known good).
// x:[B,C,N] fp32 -> Q (pre-scaled), K bf16 [B,N,C]; V bf16 [B,C,N]
// grid(8, B, 24): z -> {q,k,v} x 8-output group.  768 blocks.
// ---------------------------------------------------------------------------
__global__ __launch_bounds__(256) void qkv_kernel(
    const float* __restrict__ x, const float* __restrict__ wqkv,
    const float* __restrict__ bqkv,
    __bf16* __restrict__ Qg, __bf16* __restrict__ Kg, __bf16* __restrict__ Vg)
{
  const int tid = threadIdx.x;
  const int b = blockIdx.y;
  const int z = blockIdx.z;
  const int tsel = z >> 3;           // 0=q, 1=k, 2=v
  const int obase = (z & 7) * 8;     // which 8 output channels
  const int n = blockIdx.x * 512 + tid * 2;   // this thread: n, n+1
  const float wscale = (tsel == 0) ? QSCALE : 1.0f;

  __shared__ float wsh[8 * 64];      // 512 floats: 2 per thread
  __shared__ float bsh[8];
  wsh[tid]       = wqkv[(tsel * 64 + obase) * 64 + tid] * wscale;
  wsh[tid + 256] = wqkv[(tsel * 64 + obase) * 64 + tid + 256] * wscale;
  if (tid < 8) bsh[tid] = bqkv[tsel * 64 + obase + tid] * wscale;
  __syncthreads();

  float xa[64], xb[64];
#pragma unroll
  for (int c = 0; c < 64; c++) {
    const float2 t = *(const float2*)&x[((size_t)(b * 64 + c)) * NN + n];
    xa[c] = t.x; xb[c] = t.y;        // 8B/lane coalesced
  }

  float aa[8], ab[8];
#pragma unroll
  for (int j = 0; j < 8; j++) { aa[j] = bsh[j]; ab[j] = bsh[j]; }
#pragma unroll
  for (int c4 = 0; c4 < 64; c4 += 4) {
#pragma unroll
    for (int j = 0; j < 8; j++) {
      const float4 wv = *(const float4*)&wsh[j * 64 + c4];  // broadcast read
      aa[j] = fmaf(wv.x, xa[c4 + 0], aa[j]);
      aa[j] = fmaf(wv.y, xa[c4 + 1], aa[j]);
      aa[j] = fmaf(wv.z, xa[c4 + 2], aa[j]);
      aa[j] = fmaf(wv.w, xa[c4 + 3], aa[j]);
      ab[j] = fmaf(wv.x, xb[c4 + 0], ab[j]);
      ab[j] = fmaf(wv.y, xb[c4 + 1], ab[j]);
      ab[j] = fmaf(wv.z, xb[c4 + 2], ab[j]);
      ab[j] = fmaf(wv.w, xb[c4 + 3], ab[j]);
    }
  }

  if (tsel == 2) {
#pragma unroll
    for (int j = 0; j < 8; j++) {
      bf16x2 pv;
      pv[0] = (__bf16)aa[j]; pv[1] = (__bf16)ab[j];
      *(bf16x2*)(Vg + ((size_t)(b * 64 + obase + j)) * NN + n) = pv;
    }
  } else {
    __bf16* base = (tsel == 0 ? Qg : Kg);
    bf16x8 p0, p1;
#pragma unroll
    for (int j = 0; j < 8; j++) { p0[j] = (__bf16)aa[j]; p1[j] = (__bf16)ab[j]; }
    *(bf16x8*)(base + ((size_t)(b * NN + n)) * 64 + obase) = p0;
    *(bf16x8*)(base + ((size_t)(b * NN + n + 1)) * 64 + obase) = p1;
  }
}

// ---------------------------------------------------------------------------
// Kernel 2: flash attention, split-K, max-free softmax, FUSED PROJ EPILOGUE.
// Core is R10-exact (verified best): Kt+Vt staged LDS, 2 barriers/tile,
// S^T = mfma16x16x32(kf,qf), P in registers (S^T C/D layout == B-operand of
// mfma16x16x16bf16_1k), PV = chained K=16 MFMAs with A = V^T b64 frags.
// NEW epilogue: proj commutes with split-sum and 1/l scaling, and O^T acc
// C/D layout is AGAIN the B-operand layout of K=16 MFMA -> Po^T = Wp * O^T
// via 32 mfma16x16x16 (A = wproj float4 loads -> bf16, L2-broadcast).
// Writes PROJ-SPACE partials Opart:[S,B,C,N] bf16 (unnorm), lpart:[S,B,N].
// grid(32, B, SPLIT), 256 thr = 4 waves; wave owns 32 q, block 128 q.
// ---------------------------------------------------------------------------
__global__ __launch_bounds__(256) void flash_kernel(
    const __bf16* __restrict__ Q, const __bf16* __restrict__ K,
    const __bf16* __restrict__ V, const float* __restrict__ wproj,
    __bf16* __restrict__ Opart, float* __restrict__ lpart)
{
  const int b = blockIdx.y;
  const int s = blockIdx.z;
  const int tid = threadIdx.x;
  const int wave = tid >> 6;
  const int lane = tid & 63;
  const int quad = lane >> 4;
  const int l16 = lane & 15;

  __shared__ __bf16 Kt[64 * 72];      // [key][c], padded
  __shared__ __bf16 Vt[64 * 72];      // [c][key], padded

  const int q0 = blockIdx.x * 128 + wave * 32;

  // Q fragments (registers, loaded once)
  bf16x8 qf[2][2];
#pragma unroll
  for (int qt = 0; qt < 2; qt++) {
    const __bf16* qrow = Q + ((size_t)(b * NN + q0 + qt * 16 + l16)) * 64;
    qf[qt][0] = *(const bf16x8*)(qrow + quad * 8);
    qf[qt][1] = *(const bf16x8*)(qrow + 32 + quad * 8);
  }

  f32x4 acc[2][4];    // O^T acc: row c = ct*16+quad*4+r, col q = qt*16+l16
#pragma unroll
  for (int qt = 0; qt < 2; qt++)
#pragma unroll
    for (int ct = 0; ct < 4; ct++) acc[qt][ct] = (f32x4){0.f, 0.f, 0.f, 0.f};
  float l[2] = {0.f, 0.f};

  const int kbeg = s * (NN / SPLIT);
  const int kend = kbeg + (NN / SPLIT);
#pragma unroll 1
  for (int kt0 = kbeg; kt0 < kend; kt0 += 64) {
    __syncthreads();
#pragma unroll
    for (int it = 0; it < 2; it++) {
      const int chunk = tid + it * 256;          // 512 chunks of 8 bf16
      const int row = chunk >> 3, col8 = (chunk & 7) * 8;
      *(bf16x8*)(&Kt[row * 72 + col8]) =
          *(const bf16x8*)(K + ((size_t)(b * NN + kt0 + row)) * 64 + col8);
      *(bf16x8*)(&Vt[row * 72 + col8]) =
          *(const bf16x8*)(V + ((size_t)(b * 64 + row)) * NN + kt0 + col8);
    }
    __syncthreads();

    // ---- S^T = K Q^T, P packed into registers --------------------------
    s16x4 pk[4][2];
#pragma unroll
    for (int t = 0; t < 4; t++) {
      const bf16x8 kf0 = *(const bf16x8*)(&Kt[(t * 16 + l16) * 72 + quad * 8]);
      const bf16x8 kf1 = *(const bf16x8*)(&Kt[(t * 16 + l16) * 72 + 32 + quad * 8]);
#pragma unroll
      for (int qt = 0; qt < 2; qt++) {
        f32x4 z = (f32x4){0.f, 0.f, 0.f, 0.f};
        z = __builtin_amdgcn_mfma_f32_16x16x32_bf16(kf0, qf[qt][0], z, 0, 0, 0);
        z = __builtin_amdgcn_mfma_f32_16x16x32_bf16(kf1, qf[qt][1], z, 0, 0, 0);
        const float p0 = EXP2(z[0]), p1 = EXP2(z[1]);
        const float p2 = EXP2(z[2]), p3 = EXP2(z[3]);
        l[qt] += (p0 + p1) + (p2 + p3);
        bf16x4 pv;
        pv[0] = (__bf16)p0; pv[1] = (__bf16)p1;
        pv[2] = (__bf16)p2; pv[3] = (__bf16)p3;
        pk[t][qt] = __builtin_bit_cast(s16x4, pv);
      }
    }

    // ---- O^T += V^T P^T : K=16 MFMAs, P straight from registers --------
#pragma unroll
    for (int kg = 0; kg < 4; kg++) {
#pragma unroll
      for (int ct = 0; ct < 4; ct++) {
        const bf16x4 va =
            *(const bf16x4*)(&Vt[(ct * 16 + l16) * 72 + kg * 16 + quad * 4]);
        const s16x4 a = __builtin_bit_cast(s16x4, va);
        acc[0][ct] = __builtin_amdgcn_mfma_f32_16x16x16bf16_1k(
            a, pk[kg][0], acc[0][ct], 0, 0, 0);
        acc[1][ct] = __builtin_amdgcn_mfma_f32_16x16x16bf16_1k(
            a, pk[kg][1], acc[1][ct], 0, 0, 0);
      }
    }
  }

  // ---- epilogue 1: l reduction (2 shuffles per q-tile) ------------------
#pragma unroll
  for (int qt = 0; qt < 2; qt++) {
    float lr = l[qt];
    lr += __shfl_xor(lr, 16);
    lr += __shfl_xor(lr, 32);
    if (quad == 0)
      lpart[((size_t)(s * NB + b)) * NN + q0 + qt * 16 + l16] = lr;
  }

  // ---- epilogue 2: fused proj.  Po^T = Wp * O^T -------------------------
  // acc C/D layout: k = c = ch*16+quad*4+r, n = q  == B-operand of K=16 MFMA.
  s16x4 ob[2][4];
#pragma unroll
  for (int qt = 0; qt < 2; qt++)
#pragma unroll
    for (int ch = 0; ch < 4; ch++) {
      bf16x4 t;
#pragma unroll
      for (int r = 0; r < 4; r++) t[r] = (__bf16)acc[qt][ch][r];
      ob[qt][ch] = __builtin_bit_cast(s16x4, t);
    }

#pragma unroll
  for (int cot = 0; cot < 4; cot++) {
    f32x4 po[2];
    po[0] = (f32x4){0.f, 0.f, 0.f, 0.f};
    po[1] = (f32x4){0.f, 0.f, 0.f, 0.f};
#pragma unroll
    for (int ch = 0; ch < 4; ch++) {
      // A-frag: Wp[co = cot*16+l16][c = ch*16+quad*4+j], j=0..3
      const float4 wv =
          *(const float4*)&wproj[(cot * 16 + l16) * 64 + ch * 16 + quad * 4];
      bf16x4 wb;
      wb[0] = (__bf16)wv.x; wb[1] = (__bf16)wv.y;
      wb[2] = (__bf16)wv.z; wb[3] = (__bf16)wv.w;
      const s16x4 a = __builtin_bit_cast(s16x4, wb);
      po[0] = __builtin_amdgcn_mfma_f32_16x16x16bf16_1k(a, ob[0][ch], po[0], 0, 0, 0);
      po[1] = __builtin_amdgcn_mfma_f32_16x16x16bf16_1k(a, ob[1][ch], po[1], 0, 0, 0);
    }
    // store: co = cot*16+quad*4+r, q = q0+qt*16+l16 (16 lanes contiguous n)
#pragma unroll
    for (int qt = 0; qt < 2; qt++)
#pragma unroll
      for (int r = 0; r < 4; r++)
        Opart[(((size_t)(s * NB + b)) * 64 + cot * 16 + quad * 4 + r) * NN +
              q0 + qt * 16 + l16] = (__bf16)po[qt][r];
  }
}

// ---------------------------------------------------------------------------
// Kernel 3: slim combine — sum proj-space split partials, scale by 1/l,
// + bias + residual.  NO GEMM, near-zero LDS.
// grid(128, B) = 512 blocks; block = 32-n tile x all 64 channels.
// thread = (c = tid>>2, n-oct = tid&3): 8 n's, fully coalesced.
// ---------------------------------------------------------------------------
__global__ __launch_bounds__(256) void combine_kernel(
    const __bf16* __restrict__ Opart, const float* __restrict__ lpart,
    const float* __restrict__ bproj, const float* __restrict__ x,
    float* __restrict__ out)
{
  const int b = blockIdx.y;
  const int n0 = blockIdx.x * 32;
  const int tid = threadIdx.x;

  __shared__ float linv[32];
  if (tid < 32) {
    float lt = 0.f;
#pragma unroll
    for (int s = 0; s < SPLIT; s++)
      lt += lpart[((size_t)(s * NB + b)) * NN + n0 + tid];
    linv[tid] = 1.0f / lt;
  }
  __syncthreads();

  const int c = tid >> 2;
  const int n8 = (tid & 3) * 8;

  float o[8];
#pragma unroll
  for (int j = 0; j < 8; j++) o[j] = 0.f;
#pragma unroll
  for (int s = 0; s < SPLIT; s++) {
    const bf16x8 v = *(const bf16x8*)(
        Opart + (((size_t)(s * NB + b)) * 64 + c) * NN + n0 + n8);
#pragma unroll
    for (int j = 0; j < 8; j++) o[j] += (float)v[j];
  }

  const float bb = bproj[c];
  const float4 li0 = *(const float4*)&linv[n8];
  const float4 li1 = *(const float4*)&linv[n8 + 4];
  const size_t base = ((size_t)(b * 64 + c)) * NN + n0 + n8;
  const float4 x0 = *(const float4*)&x[base];
  const float4 x1 = *(const float4*)&x[base + 4];
  float4 r0, r1;
  r0.x = o[0] * li0.x + bb + x0.x;  r0.y = o[1] * li0.y + bb + x0.y;
  r0.z = o[2] * li0.z + bb + x0.z;  r0.w = o[3] * li0.w + bb + x0.w;
  r1.x = o[4] * li1.x + bb + x1.x;  r1.y = o[5] * li1.y + bb + x1.y;
  r1.z = o[6] * li1.z + bb + x1.z;  r1.w = o[7] * li1.w + bb + x1.w;
  *(float4*)&out[base] = r0;
  *(float4*)&out[base + 4] = r1;
}

extern "C" void kernel_launch(void* const* d_in, const int* in_sizes, int n_in,
                              void* d_out, int out_size, void* d_ws, size_t ws_size,
                              hipStream_t stream) {
  const float* x     = (const float*)d_in[0];
  const float* wqkv  = (const float*)d_in[1];
  const float* bqkv  = (const float*)d_in[2];
  const float* wproj = (const float*)d_in[3];
  const float* bproj = (const float*)d_in[4];
  float* out = (float*)d_out;

  // Workspace: Q[0,2M) K[2,4M) V[4,6M) Opart[6,22M) lpart[23,23.5M)
  char* ws = (char*)d_ws;
  __bf16* Q     = (__bf16*)(ws);
  __bf16* K     = (__bf16*)(ws + (2u << 20));
  __bf16* V     = (__bf16*)(ws + (4u << 20));
  __bf16* Opart = (__bf16*)(ws + (6u << 20));   // [S,B,C,N] = 16 MiB
  float*  lpart = (float*)(ws + (23u << 20));   // SPLIT*B*N*4 = 512 KiB

  qkv_kernel<<<dim3(8, NB, 24), 256, 0, stream>>>(x, wqkv, bqkv, Q, K, V);
  flash_kernel<<<dim3(32, NB, SPLIT), 256, 0, stream>>>(Q, K, V, wproj,
                                                        Opart, lpart);
  combine_kernel<<<dim3(128, NB), 256, 0, stream>>>(Opart, lpart, bproj, x,
                                                    out);
}

// Round 14
// 113.456 us; speedup vs baseline: 1.1906x; 1.0148x over previous
//
#include <hip/hip_runtime.h>

typedef __bf16 bf16x8 __attribute__((ext_vector_type(8)));
typedef __bf16 bf16x4 __attribute__((ext_vector_type(4)));
typedef float f32x4 __attribute__((ext_vector_type(4)));
typedef short s16x4 __attribute__((ext_vector_type(4)));

#define NB 4
#define NC 64
#define NN 4096
#define SPLIT 8   // key-dim splits for flash

// sc folded into Q at qkv time: softmax uses exp2(q.k * 0.125 * log2(e))
#define QSCALE (0.125f * 1.44269504088896340736f)

#if __has_builtin(__builtin_amdgcn_exp2f)
#define EXP2(x) __builtin_amdgcn_exp2f(x)   // raw v_exp_f32; inputs are O(1)
#else
#define EXP2(x) exp2f(x)
#endif

// ---------------------------------------------------------------------------
// Kernel 1: QKV projection via MFMA, LDS-free, barrier-free.
// out^T[n, oc] = x^T W^T using mfma_16x16x32_bf16:
//   A = x^T frag  A[m=n(l16)][k=c(quad*8+j)] -- direct global loads; per
//       instr 16 lanes are n-contiguous -> 4 fully-used lines (coalesced).
//   B = W^T frag  B[k=c][n=oc(l16)] -- preloaded once per wave (fp32->bf16,
//       QSCALE folded for tsel==0).
//   D row=quad*4+r = n-offset, col=l16 = oc  -> Q/K [B,N,C] stores coalesced;
//       V [B,C,N] stored as packed bf16x4 (4 contiguous n per lane).
// grid(32, B, 3): z = tensor; block = 128 n; wave = 32 n.  384 blocks.
// ---------------------------------------------------------------------------
__global__ __launch_bounds__(256) void qkv_kernel(
    const float* __restrict__ x, const float* __restrict__ wqkv,
    const float* __restrict__ bqkv,
    __bf16* __restrict__ Qg, __bf16* __restrict__ Kg, __bf16* __restrict__ Vg)
{
  const int tid = threadIdx.x;
  const int wave = tid >> 6;
  const int lane = tid & 63;
  const int quad = lane >> 4;
  const int l16 = lane & 15;
  const int b = blockIdx.y;
  const int tsel = blockIdx.z;                 // 0=q, 1=k, 2=v
  const int n0 = blockIdx.x * 128 + wave * 32; // wave's 32 n
  const float wscale = (tsel == 0) ? QSCALE : 1.0f;

  // preload W^T B-frags: [ot][ch]; oc = ot*16+l16, c = ch*32+quad*8+j
  bf16x8 wf[4][2];
#pragma unroll
  for (int ot = 0; ot < 4; ot++) {
#pragma unroll
    for (int ch = 0; ch < 2; ch++) {
      const float* wp =
          wqkv + (size_t)(tsel * 64 + ot * 16 + l16) * 64 + ch * 32 + quad * 8;
      const float4 w0 = *(const float4*)wp;
      const float4 w1 = *(const float4*)(wp + 4);
      bf16x8 f;
      f[0] = (__bf16)(w0.x * wscale); f[1] = (__bf16)(w0.y * wscale);
      f[2] = (__bf16)(w0.z * wscale); f[3] = (__bf16)(w0.w * wscale);
      f[4] = (__bf16)(w1.x * wscale); f[5] = (__bf16)(w1.y * wscale);
      f[6] = (__bf16)(w1.z * wscale); f[7] = (__bf16)(w1.w * wscale);
      wf[ot][ch] = f;
    }
  }
  float bv[4];
#pragma unroll
  for (int ot = 0; ot < 4; ot++)
    bv[ot] = bqkv[tsel * 64 + ot * 16 + l16] * wscale;

#pragma unroll
  for (int nt = 0; nt < 2; nt++) {
    const int nb = n0 + nt * 16 + l16;

    // A-frags: x^T[n][c] for c-halves; direct global, 4 lines/instr
    bf16x8 xf[2];
#pragma unroll
    for (int ch = 0; ch < 2; ch++) {
      float v[8];
#pragma unroll
      for (int j = 0; j < 8; j++)
        v[j] = x[(size_t)(b * 64 + ch * 32 + quad * 8 + j) * NN + nb];
      bf16x8 f;
#pragma unroll
      for (int j = 0; j < 8; j++) f[j] = (__bf16)v[j];
      xf[ch] = f;
    }

#pragma unroll
    for (int ot = 0; ot < 4; ot++) {
      f32x4 acc = (f32x4){bv[ot], bv[ot], bv[ot], bv[ot]};
      acc = __builtin_amdgcn_mfma_f32_16x16x32_bf16(xf[0], wf[ot][0], acc, 0, 0, 0);
      acc = __builtin_amdgcn_mfma_f32_16x16x32_bf16(xf[1], wf[ot][1], acc, 0, 0, 0);

      if (tsel < 2) {
        __bf16* dst = (tsel == 0) ? Qg : Kg;
#pragma unroll
        for (int r = 0; r < 4; r++)
          dst[(size_t)(b * NN + n0 + nt * 16 + quad * 4 + r) * 64 + ot * 16 + l16] =
              (__bf16)acc[r];
      } else {
        bf16x4 pv;
#pragma unroll
        for (int r = 0; r < 4; r++) pv[r] = (__bf16)acc[r];
        *(bf16x4*)(Vg + (size_t)(b * 64 + ot * 16 + l16) * NN +
                   n0 + nt * 16 + quad * 4) = pv;
      }
    }
  }
}

// ---------------------------------------------------------------------------
// Kernel 2: flash attention, split-K, max-free softmax, FUSED PROJ EPILOGUE.
// (R13-exact.)  Kt+Vt staged LDS, 2 barriers/tile; S^T = mfma16x16x32(kf,qf);
// P in registers (S^T C/D layout == B-operand of mfma16x16x16bf16_1k);
// PV = chained K=16 MFMAs, A = V^T b64 frags; epilogue Po^T = Wp * O^T.
// Opart:[S,B,C,N] bf16 (unnorm, proj-space), lpart:[S,B,N].
// grid(32, B, SPLIT), 256 thr = 4 waves; wave owns 32 q, block 128 q.
// ---------------------------------------------------------------------------
__global__ __launch_bounds__(256) void flash_kernel(
    const __bf16* __restrict__ Q, const __bf16* __restrict__ K,
    const __bf16* __restrict__ V, const float* __restrict__ wproj,
    __bf16* __restrict__ Opart, float* __restrict__ lpart)
{
  const int b = blockIdx.y;
  const int s = blockIdx.z;
  const int tid = threadIdx.x;
  const int wave = tid >> 6;
  const int lane = tid & 63;
  const int quad = lane >> 4;
  const int l16 = lane & 15;

  __shared__ __bf16 Kt[64 * 72];      // [key][c], padded
  __shared__ __bf16 Vt[64 * 72];      // [c][key], padded

  const int q0 = blockIdx.x * 128 + wave * 32;

  bf16x8 qf[2][2];
#pragma unroll
  for (int qt = 0; qt < 2; qt++) {
    const __bf16* qrow = Q + ((size_t)(b * NN + q0 + qt * 16 + l16)) * 64;
    qf[qt][0] = *(const bf16x8*)(qrow + quad * 8);
    qf[qt][1] = *(const bf16x8*)(qrow + 32 + quad * 8);
  }

  f32x4 acc[2][4];    // O^T acc: row c = ct*16+quad*4+r, col q = qt*16+l16
#pragma unroll
  for (int qt = 0; qt < 2; qt++)
#pragma unroll
    for (int ct = 0; ct < 4; ct++) acc[qt][ct] = (f32x4){0.f, 0.f, 0.f, 0.f};
  float l[2] = {0.f, 0.f};

  const int kbeg = s * (NN / SPLIT);
  const int kend = kbeg + (NN / SPLIT);
#pragma unroll 1
  for (int kt0 = kbeg; kt0 < kend; kt0 += 64) {
    __syncthreads();
#pragma unroll
    for (int it = 0; it < 2; it++) {
      const int chunk = tid + it * 256;          // 512 chunks of 8 bf16
      const int row = chunk >> 3, col8 = (chunk & 7) * 8;
      *(bf16x8*)(&Kt[row * 72 + col8]) =
          *(const bf16x8*)(K + ((size_t)(b * NN + kt0 + row)) * 64 + col8);
      *(bf16x8*)(&Vt[row * 72 + col8]) =
          *(const bf16x8*)(V + ((size_t)(b * 64 + row)) * NN + kt0 + col8);
    }
    __syncthreads();

    // ---- S^T = K Q^T, P packed into registers --------------------------
    s16x4 pk[4][2];
#pragma unroll
    for (int t = 0; t < 4; t++) {
      const bf16x8 kf0 = *(const bf16x8*)(&Kt[(t * 16 + l16) * 72 + quad * 8]);
      const bf16x8 kf1 = *(const bf16x8*)(&Kt[(t * 16 + l16) * 72 + 32 + quad * 8]);
#pragma unroll
      for (int qt = 0; qt < 2; qt++) {
        f32x4 z = (f32x4){0.f, 0.f, 0.f, 0.f};
        z = __builtin_amdgcn_mfma_f32_16x16x32_bf16(kf0, qf[qt][0], z, 0, 0, 0);
        z = __builtin_amdgcn_mfma_f32_16x16x32_bf16(kf1, qf[qt][1], z, 0, 0, 0);
        const float p0 = EXP2(z[0]), p1 = EXP2(z[1]);
        const float p2 = EXP2(z[2]), p3 = EXP2(z[3]);
        l[qt] += (p0 + p1) + (p2 + p3);
        bf16x4 pv;
        pv[0] = (__bf16)p0; pv[1] = (__bf16)p1;
        pv[2] = (__bf16)p2; pv[3] = (__bf16)p3;
        pk[t][qt] = __builtin_bit_cast(s16x4, pv);
      }
    }

    // ---- O^T += V^T P^T : K=16 MFMAs, P straight from registers --------
#pragma unroll
    for (int kg = 0; kg < 4; kg++) {
#pragma unroll
      for (int ct = 0; ct < 4; ct++) {
        const bf16x4 va =
            *(const bf16x4*)(&Vt[(ct * 16 + l16) * 72 + kg * 16 + quad * 4]);
        const s16x4 a = __builtin_bit_cast(s16x4, va);
        acc[0][ct] = __builtin_amdgcn_mfma_f32_16x16x16bf16_1k(
            a, pk[kg][0], acc[0][ct], 0, 0, 0);
        acc[1][ct] = __builtin_amdgcn_mfma_f32_16x16x16bf16_1k(
            a, pk[kg][1], acc[1][ct], 0, 0, 0);
      }
    }
  }

  // ---- epilogue 1: l reduction (2 shuffles per q-tile) ------------------
#pragma unroll
  for (int qt = 0; qt < 2; qt++) {
    float lr = l[qt];
    lr += __shfl_xor(lr, 16);
    lr += __shfl_xor(lr, 32);
    if (quad == 0)
      lpart[((size_t)(s * NB + b)) * NN + q0 + qt * 16 + l16] = lr;
  }

  // ---- epilogue 2: fused proj.  Po^T = Wp * O^T -------------------------
  s16x4 ob[2][4];
#pragma unroll
  for (int qt = 0; qt < 2; qt++)
#pragma unroll
    for (int ch = 0; ch < 4; ch++) {
      bf16x4 t;
#pragma unroll
      for (int r = 0; r < 4; r++) t[r] = (__bf16)acc[qt][ch][r];
      ob[qt][ch] = __builtin_bit_cast(s16x4, t);
    }

#pragma unroll
  for (int cot = 0; cot < 4; cot++) {
    f32x4 po[2];
    po[0] = (f32x4){0.f, 0.f, 0.f, 0.f};
    po[1] = (f32x4){0.f, 0.f, 0.f, 0.f};
#pragma unroll
    for (int ch = 0; ch < 4; ch++) {
      const float4 wv =
          *(const float4*)&wproj[(cot * 16 + l16) * 64 + ch * 16 + quad * 4];
      bf16x4 wb;
      wb[0] = (__bf16)wv.x; wb[1] = (__bf16)wv.y;
      wb[2] = (__bf16)wv.z; wb[3] = (__bf16)wv.w;
      const s16x4 a = __builtin_bit_cast(s16x4, wb);
      po[0] = __builtin_amdgcn_mfma_f32_16x16x16bf16_1k(a, ob[0][ch], po[0], 0, 0, 0);
      po[1] = __builtin_amdgcn_mfma_f32_16x16x16bf16_1k(a, ob[1][ch], po[1], 0, 0, 0);
    }
#pragma unroll
    for (int qt = 0; qt < 2; qt++)
#pragma unroll
      for (int r = 0; r < 4; r++)
        Opart[(((size_t)(s * NB + b)) * 64 + cot * 16 + quad * 4 + r) * NN +
              q0 + qt * 16 + l16] = (__bf16)po[qt][r];
  }
}

// ---------------------------------------------------------------------------
// Kernel 3: slim combine (R13-exact) — sum proj-space split partials, 1/l,
// + bias + residual.  grid(128, B); thread = (c, n-oct), coalesced.
// ---------------------------------------------------------------------------
__global__ __launch_bounds__(256) void combine_kernel(
    const __bf16* __restrict__ Opart, const float* __restrict__ lpart,
    const float* __restrict__ bproj, const float* __restrict__ x,
    float* __restrict__ out)
{
  const int b = blockIdx.y;
  const int n0 = blockIdx.x * 32;
  const int tid = threadIdx.x;

  __shared__ float linv[32];
  if (tid < 32) {
    float lt = 0.f;
#pragma unroll
    for (int s = 0; s < SPLIT; s++)
      lt += lpart[((size_t)(s * NB + b)) * NN + n0 + tid];
    linv[tid] = 1.0f / lt;
  }
  __syncthreads();

  const int c = tid >> 2;
  const int n8 = (tid & 3) * 8;

  float o[8];
#pragma unroll
  for (int j = 0; j < 8; j++) o[j] = 0.f;
#pragma unroll
  for (int s = 0; s < SPLIT; s++) {
    const bf16x8 v = *(const bf16x8*)(
        Opart + (((size_t)(s * NB + b)) * 64 + c) * NN + n0 + n8);
#pragma unroll
    for (int j = 0; j < 8; j++) o[j] += (float)v[j];
  }

  const float bb = bproj[c];
  const float4 li0 = *(const float4*)&linv[n8];
  const float4 li1 = *(const float4*)&linv[n8 + 4];
  const size_t base = ((size_t)(b * 64 + c)) * NN + n0 + n8;
  const float4 x0 = *(const float4*)&x[base];
  const float4 x1 = *(const float4*)&x[base + 4];
  float4 r0, r1;
  r0.x = o[0] * li0.x + bb + x0.x;  r0.y = o[1] * li0.y + bb + x0.y;
  r0.z = o[2] * li0.z + bb + x0.z;  r0.w = o[3] * li0.w + bb + x0.w;
  r1.x = o[4] * li1.x + bb + x1.x;  r1.y = o[5] * li1.y + bb + x1.y;
  r1.z = o[6] * li1.z + bb + x1.z;  r1.w = o[7] * li1.w + bb + x1.w;
  *(float4*)&out[base] = r0;
  *(float4*)&out[base + 4] = r1;
}

extern "C" void kernel_launch(void* const* d_in, const int* in_sizes, int n_in,
                              void* d_out, int out_size, void* d_ws, size_t ws_size,
                              hipStream_t stream) {
  const float* x     = (const float*)d_in[0];
  const float* wqkv  = (const float*)d_in[1];
  const float* bqkv  = (const float*)d_in[2];
  const float* wproj = (const float*)d_in[3];
  const float* bproj = (const float*)d_in[4];
  float* out = (float*)d_out;

  // Workspace: Q[0,2M) K[2,4M) V[4,6M) Opart[6,22M) lpart[23,23.5M)
  char* ws = (char*)d_ws;
  __bf16* Q     = (__bf16*)(ws);
  __bf16* K     = (__bf16*)(ws + (2u << 20));
  __bf16* V     = (__bf16*)(ws + (4u << 20));
  __bf16* Opart = (__bf16*)(ws + (6u << 20));   // [S,B,C,N] = 16 MiB
  float*  lpart = (float*)(ws + (23u << 20));   // SPLIT*B*N*4 = 512 KiB

  qkv_kernel<<<dim3(32, NB, 3), 256, 0, stream>>>(x, wqkv, bqkv, Q, K, V);
  flash_kernel<<<dim3(32, NB, SPLIT), 256, 0, stream>>>(Q, K, V, wproj,
                                                        Opart, lpart);
  combine_kernel<<<dim3(128, NB), 256, 0, stream>>>(Opart, lpart, bproj, x,
                                                    out);
}